// Round 7
// baseline (442.888 us; speedup 1.0000x reference)
//
#include <hip/hip_runtime.h>
#include <hip/hip_bf16.h>

// Problem constants
#define NNODES 100000
#define NEDGES 300000
#define FIN 128
#define HDIM 256
#define NLAYERS 3
#define MPAD 100096  // 782 * 128 — all GEMMs compute exactly MPAD rows, no predicates

typedef float f32x4 __attribute__((ext_vector_type(4)));
typedef short bf16x8 __attribute__((ext_vector_type(8)));

__device__ inline float bf2f(unsigned short u) {
    union { unsigned int i; float f; } v;
    v.i = ((unsigned int)u) << 16;
    return v.f;
}
__device__ inline unsigned short f2bf(float f) {  // RNE
    union { float f; unsigned int i; } v;
    v.f = f;
    return (unsigned short)((v.i + 0x7fffu + ((v.i >> 16) & 1u)) >> 16);
}

// 16-byte async global->LDS (dest = wave-uniform base + lane*16)
__device__ __forceinline__ void gll16(const unsigned short* g, unsigned short* l) {
    __builtin_amdgcn_global_load_lds(
        (const __attribute__((address_space(1))) unsigned int*)g,
        (__attribute__((address_space(3))) unsigned int*)l, 16, 0, 0);
}

// ---------------------------------------------------------------------------
// Counted-vmcnt pipelined MFMA GEMM (R3 structure + R5 XCD pair-swizzle +
// R7 swapped-operand epilogue).
// 128x128 tile, 4 waves, BK=32, TRIPLE-buffered LDS (48 KiB, 3 blocks/CU).
// Per K-step: vmcnt(4) -> s_barrier -> issue stage(t+2) -> ds_read buf[t%3]
// -> 16 MFMA.  (Race audit in R3 notes; unchanged.)
// XCD PAIR-SWIZZLE: 1-D grid, bid = 16t + 8x + u (u=0..7), y = 8t+u; the two
// col-tiles of row-panel y sit 8 apart -> same XCD, co-resident -> A L2-hits.
// SWAPPED OPERANDS: acc[i][j] = mfma(b[j], a[i], acc) gives D layout
// lane&15 = C-row, kq*4+reg = 4 CONSECUTIVE C-cols -> ushort4 epilogue
// (16x 8B stores/thread vs 64x 2B).  Numerically validated in R4.
// ---------------------------------------------------------------------------
template <int K, bool BIAS, bool RELU>
__global__ __launch_bounds__(256) void gemm_lds_k(
    const unsigned short* __restrict__ A, const unsigned short* __restrict__ Bt,
    const float* __restrict__ bias, unsigned short* __restrict__ C, int my) {
    constexpr int BK = 32;        // 64 B per LDS row
    constexpr int NT = K / BK;    // 4 (K=128) or 8 (K=256)
    __shared__ unsigned short sA[3][128 * BK];
    __shared__ unsigned short sB[3][128 * BK];

    const int bid   = blockIdx.x;
    const int ytile = (bid >> 4) * 8 + (bid & 7);
    if (ytile >= my) return;               // uniform whole-block exit, pre-barrier
    const int xcol  = (bid >> 3) & 1;
    const int rowblk = ytile * 128;
    const int colblk = xcol * 128;

    const int tid  = threadIdx.x;
    const int lane = tid & 63;
    const int wid  = tid >> 6;
    const int r15  = lane & 15;
    const int kq   = lane >> 4;        // 0..3
    const int wr   = wid >> 1;         // wave row-tile (0/1)
    const int wc   = wid & 1;          // wave col-tile (0/1)

    // Staging geometry: wave w, chunk q covers LDS rows [q*64 + w*16, +16),
    // each row = 64 B; lane L writes row (L>>2), phys slot (L&3).
    // Phys slot p at row r holds logical k-slot p ^ ((r>>1)&3)  (involution).
    const unsigned short* gA[2];
    const unsigned short* gB[2];
    int ldsbase[2];
#pragma unroll
    for (int q = 0; q < 2; ++q) {
        int rr   = q * 64 + wid * 16 + (lane >> 2);
        int slot = (lane & 3) ^ ((rr >> 1) & 3);
        gA[q] = A  + (size_t)(rowblk + rr) * K + slot * 8;
        gB[q] = Bt + (size_t)(colblk + rr) * K + slot * 8;
        ldsbase[q] = (q * 64 + wid * 16) * BK;   // wave-uniform
    }

    // Read-side swizzled fragment offsets (elements)
    const int sread = ((kq ^ ((r15 >> 1) & 3)) * 8);
    int aoff[4], boff[4];
#pragma unroll
    for (int i = 0; i < 4; ++i) {
        aoff[i] = (wr * 64 + i * 16 + r15) * BK + sread;
        boff[i] = (wc * 64 + i * 16 + r15) * BK + sread;
    }

    f32x4 acc[4][4] = {};

    // prologue: stage K-tiles 0 and 1 into bufs 0 and 1 (8 loads in flight)
#pragma unroll
    for (int q = 0; q < 2; ++q) {
        gll16(gA[q], &sA[0][ldsbase[q]]);
        gll16(gB[q], &sB[0][ldsbase[q]]);
    }
#pragma unroll
    for (int q = 0; q < 2; ++q) {
        gll16(gA[q] + BK, &sA[1][ldsbase[q]]);
        gll16(gB[q] + BK, &sB[1][ldsbase[q]]);
    }

#pragma unroll
    for (int t = 0; t < NT; ++t) {
        // counted drain: only stage(t) must have landed; stage(t+1) stays in flight
        if (t + 1 < NT) {
            asm volatile("s_waitcnt vmcnt(4)" ::: "memory");
        } else {
            asm volatile("s_waitcnt vmcnt(0)" ::: "memory");
        }
        __builtin_amdgcn_s_barrier();
        // issue stage(t+2) AFTER the barrier (its buffer's last readers were
        // iter t-1, all retired before any wave passed this barrier)
        if (t + 2 < NT) {
#pragma unroll
            for (int q = 0; q < 2; ++q) {
                gll16(gA[q] + (t + 2) * BK, &sA[(t + 2) % 3][ldsbase[q]]);
                gll16(gB[q] + (t + 2) * BK, &sB[(t + 2) % 3][ldsbase[q]]);
            }
        }
        bf16x8 a[4], b[4];
#pragma unroll
        for (int i = 0; i < 4; ++i) a[i] = *(const bf16x8*)&sA[t % 3][aoff[i]];
#pragma unroll
        for (int j = 0; j < 4; ++j) b[j] = *(const bf16x8*)&sB[t % 3][boff[j]];
        // swapped operands: lane&15 = C-row, kq*4+reg = C-col
#pragma unroll
        for (int i = 0; i < 4; ++i)
#pragma unroll
            for (int j = 0; j < 4; ++j)
                acc[i][j] = __builtin_amdgcn_mfma_f32_16x16x32_bf16(b[j], a[i], acc[i][j], 0, 0, 0);
    }

    // Epilogue: lane holds C[row][colb..colb+3] per frag — one 8B store each
#pragma unroll
    for (int i = 0; i < 4; ++i) {
        int row = rowblk + wr * 64 + i * 16 + r15;
#pragma unroll
        for (int j = 0; j < 4; ++j) {
            int colb = colblk + wc * 64 + j * 16 + kq * 4;
            float v0 = acc[i][j][0], v1 = acc[i][j][1], v2 = acc[i][j][2], v3 = acc[i][j][3];
            if (BIAS) {
                float4 bb = ((const float4*)bias)[colb >> 2];
                v0 += bb.x; v1 += bb.y; v2 += bb.z; v3 += bb.w;
            }
            if (RELU) {
                v0 = fmaxf(v0, 0.0f); v1 = fmaxf(v1, 0.0f);
                v2 = fmaxf(v2, 0.0f); v3 = fmaxf(v3, 0.0f);
            }
            ushort4 o;
            o.x = f2bf(v0); o.y = f2bf(v1); o.z = f2bf(v2); o.w = f2bf(v3);
            *(ushort4*)&C[(size_t)row * HDIM + colb] = o;
        }
    }
}

// ---------------------------------------------------------------------------
// Merged prep kernel, partitioned by blockIdx over 6 independent jobs:
//   [0,12500):      conv x -> xb   (fp32->bf16, x4)   [N*FIN/4 = 3.2M items]
//   [12500,12628):  wprep w1 -> w1t  (transpose+convert, K=FIN)
//   [12628,13396):  wprep gw -> gwt  (3 mats, K=HDIM)
//   [13396,13460):  conv w2 -> w2c
//   [13460,13851):  zero cnt (NNODES)
//   [13851]:        foldbias fb[c] = sum_j b2[j]*G0[j][c]
// ---------------------------------------------------------------------------
__global__ __launch_bounds__(256) void prep_k(
    const float* __restrict__ x, unsigned short* __restrict__ xb,
    const float* __restrict__ w1, unsigned short* __restrict__ w1t,
    const float* __restrict__ gw, unsigned short* __restrict__ gwt,
    const float* __restrict__ w2, unsigned short* __restrict__ w2c,
    const float* __restrict__ b2, float* __restrict__ foldb,
    unsigned* __restrict__ cnt) {
    int b = blockIdx.x;
    int tid = threadIdx.x;
    if (b < 12500) {                     // conv x (x4)
        int i = b * 256 + tid;           // < 3,200,000
        float4 v = ((const float4*)x)[i];
        ushort4 u;
        u.x = f2bf(v.x); u.y = f2bf(v.y); u.z = f2bf(v.z); u.w = f2bf(v.w);
        ((ushort4*)xb)[i] = u;
    } else if (b < 12628) {              // wprep w1: [FIN][256] -> [256][FIN]
        int i = (b - 12500) * 256 + tid; // < 32768
        int k = i >> 8, p = i & 255;
        w1t[(size_t)p * FIN + k] = f2bf(w1[i]);
    } else if (b < 13396) {              // wprep gw: [3][256][256] -> transposed
        int i = (b - 12628) * 256 + tid; // < 196608
        int mat = i >> 16;
        int r = i & 65535;
        int k = r >> 8, p = r & 255;
        gwt[(size_t)mat * 65536 + (size_t)p * HDIM + k] = f2bf(gw[i]);
    } else if (b < 13460) {              // conv w2 (x4): 16384 float4s
        int i = (b - 13396) * 256 + tid;
        float4 v = ((const float4*)w2)[i];
        ushort4 u;
        u.x = f2bf(v.x); u.y = f2bf(v.y); u.z = f2bf(v.z); u.w = f2bf(v.w);
        ((ushort4*)w2c)[i] = u;
    } else if (b < 13851) {              // zero cnt
        int i = (b - 13460) * 256 + tid;
        if (i < NNODES) cnt[i] = 0u;
    } else {                             // foldbias (one block)
        int c = tid;
        float s = 0.0f;
#pragma unroll 8
        for (int j = 0; j < HDIM; ++j) s += b2[j] * gw[(size_t)j * HDIM + c];
        foldb[c] = s;
    }
}

// ---------------------------------------------------------------------------
// CSR build utilities
// ---------------------------------------------------------------------------
__global__ void count_k(const int* __restrict__ dst, unsigned* __restrict__ cnt, int E) {
    int e = blockIdx.x * blockDim.x + threadIdx.x;
    if (e < E) atomicAdd(&cnt[dst[e]], 1u);
}

// scan1 also computes dinv and zeroes cnt (cursor reuse)
__global__ __launch_bounds__(256) void scan1_k(unsigned* __restrict__ cnt,
                                               int* __restrict__ rs,
                                               unsigned* __restrict__ blocksum,
                                               float* __restrict__ dinv, int N) {
    __shared__ unsigned tmp[256];
    int tid = threadIdx.x;
    int gid = blockIdx.x * 256 + tid;
    unsigned v = (gid < N) ? cnt[gid] : 0u;
    if (gid < N) {
        dinv[gid] = 1.0f / sqrtf((float)(v + 1u));  // +1 = self loop
        cnt[gid] = 0u;                               // reset for cursor use
    }
    tmp[tid] = v;
    __syncthreads();
#pragma unroll
    for (int off = 1; off < 256; off <<= 1) {
        unsigned t = (tid >= off) ? tmp[tid - off] : 0u;
        __syncthreads();
        tmp[tid] += t;
        __syncthreads();
    }
    if (gid < N) rs[gid] = (int)(tmp[tid] - v);
    if (tid == 255) blocksum[blockIdx.x] = tmp[tid];
}

// scan23: merged scan2+scan3. Each block b reduces the RAW per-block totals
// blocksum[0..b) itself (<=391 values, 2 strided loads/thread + block
// reduce), then adds that prefix to its rs slice.  Saves one launch.
__global__ __launch_bounds__(256) void scan23_k(int* __restrict__ rs,
                                                const unsigned* __restrict__ blocksum,
                                                int N, int E) {
    const int b = blockIdx.x, tid = threadIdx.x;
    unsigned s = 0;
    for (int i = tid; i < b; i += 256) s += blocksum[i];
    __shared__ unsigned red[4];
#pragma unroll
    for (int off = 32; off > 0; off >>= 1) s += __shfl_down(s, off);
    if ((tid & 63) == 0) red[tid >> 6] = s;
    __syncthreads();
    unsigned pref = red[0] + red[1] + red[2] + red[3];
    int gid = b * 256 + tid;
    if (gid < N) rs[gid] += (int)pref;
    if (gid == N) rs[N] = E;
}

// fill_k packs (src, weight) into one int2 per edge — single 8B load in gather
__global__ void fill_k(const int* __restrict__ src, const int* __restrict__ dst,
                       const int* __restrict__ rs, unsigned* __restrict__ cursor,
                       const float* __restrict__ dinv,
                       int2* __restrict__ edata, int E) {
    int e = blockIdx.x * blockDim.x + threadIdx.x;
    if (e >= E) return;
    int s = src[e], d = dst[e];
    int pos = rs[d] + (int)atomicAdd(&cursor[d], 1u);
    float w = dinv[s] * dinv[d];
    edata[pos] = make_int2(s, __float_as_int(w));
}

// ---------------------------------------------------------------------------
// CSR gather-aggregate (bf16 m), fused self-loop + bias + ReLU.
// FOUR nodes per wave: quarter-wave (16 lanes x 32B = 512B) per node row.
// 4x independent latency chains per wave; 6250 blocks (16 nodes/block).
// Cooperative quarter-wave edge-metadata load + quarter shuffle broadcast +
// 4-wide unrolled independent row gathers. Masked slots carry (s=0, w=0.0):
// weight-0 read of row 0 contributes exactly 0.
// N divisible by 16 (100000 = 6250*16) — no tail predicate.
// ---------------------------------------------------------------------------
template <bool OUTF32>
__global__ __launch_bounds__(256) void gather_k(const int* __restrict__ rs,
                                                const int2* __restrict__ edata,
                                                const float* __restrict__ dinv,
                                                const unsigned short* __restrict__ m,
                                                const float* __restrict__ bias,
                                                void* __restrict__ out, int N) {
    const int wid  = threadIdx.x >> 6;   // 0..3
    const int lane = threadIdx.x & 63;
    const int q    = lane >> 4;          // 0..3: which node of the quad
    const int ql   = lane & 15;          // lane within quarter
    const int node = blockIdx.x * 16 + wid * 4 + q;

    const int beg = rs[node], end = rs[node + 1];
    const float d = dinv[node];
    const float w0 = d * d;

    // self row: 16 lanes x 2 bf16x8 = 512B
    const bf16x8* mrow = (const bf16x8*)(m + (size_t)node * HDIM);
    bf16x8 u0 = mrow[ql * 2], u1 = mrow[ql * 2 + 1];
    float acc[16];
#pragma unroll
    for (int j = 0; j < 8; ++j) {
        acc[j]     = bf2f((unsigned short)u0[j]) * w0;
        acc[8 + j] = bf2f((unsigned short)u1[j]) * w0;
    }

    for (int base = beg; base < end; base += 16) {
        int2 ed = (base + ql < end) ? edata[base + ql] : make_int2(0, 0);
        int take = end - base;
        if (take > 16) take = 16;
        for (int e = 0; e < take; e += 4) {
            int s0 = __shfl(ed.x, q * 16 + e + 0);
            int s1 = __shfl(ed.x, q * 16 + e + 1);
            int s2 = __shfl(ed.x, q * 16 + e + 2);
            int s3 = __shfl(ed.x, q * 16 + e + 3);
            float wq0 = __int_as_float(__shfl(ed.y, q * 16 + e + 0));
            float wq1 = __int_as_float(__shfl(ed.y, q * 16 + e + 1));
            float wq2 = __int_as_float(__shfl(ed.y, q * 16 + e + 2));
            float wq3 = __int_as_float(__shfl(ed.y, q * 16 + e + 3));
            const bf16x8* r0 = (const bf16x8*)(m + (size_t)s0 * HDIM);
            const bf16x8* r1 = (const bf16x8*)(m + (size_t)s1 * HDIM);
            const bf16x8* r2 = (const bf16x8*)(m + (size_t)s2 * HDIM);
            const bf16x8* r3 = (const bf16x8*)(m + (size_t)s3 * HDIM);
            bf16x8 v00 = r0[ql * 2], v01 = r0[ql * 2 + 1];
            bf16x8 v10 = r1[ql * 2], v11 = r1[ql * 2 + 1];
            bf16x8 v20 = r2[ql * 2], v21 = r2[ql * 2 + 1];
            bf16x8 v30 = r3[ql * 2], v31 = r3[ql * 2 + 1];
#pragma unroll
            for (int j = 0; j < 8; ++j) {
                acc[j]     += bf2f((unsigned short)v00[j]) * wq0;
                acc[8 + j] += bf2f((unsigned short)v01[j]) * wq0;
                acc[j]     += bf2f((unsigned short)v10[j]) * wq1;
                acc[8 + j] += bf2f((unsigned short)v11[j]) * wq1;
                acc[j]     += bf2f((unsigned short)v20[j]) * wq2;
                acc[8 + j] += bf2f((unsigned short)v21[j]) * wq2;
                acc[j]     += bf2f((unsigned short)v30[j]) * wq3;
                acc[8 + j] += bf2f((unsigned short)v31[j]) * wq3;
            }
        }
    }

    // bias + ReLU on 16 cols (ql*16 .. ql*16+15)
    float4 b0 = ((const float4*)bias)[ql * 4];
    float4 b1 = ((const float4*)bias)[ql * 4 + 1];
    float4 b2 = ((const float4*)bias)[ql * 4 + 2];
    float4 b3 = ((const float4*)bias)[ql * 4 + 3];
    float bb[16] = {b0.x, b0.y, b0.z, b0.w, b1.x, b1.y, b1.z, b1.w,
                    b2.x, b2.y, b2.z, b2.w, b3.x, b3.y, b3.z, b3.w};
#pragma unroll
    for (int j = 0; j < 16; ++j) acc[j] = fmaxf(acc[j] + bb[j], 0.0f);

    if (OUTF32) {
#pragma unroll
        for (int k = 0; k < 4; ++k) {
            float4 o = {acc[k * 4], acc[k * 4 + 1], acc[k * 4 + 2], acc[k * 4 + 3]};
            ((float4*)out)[(size_t)node * 64 + ql * 4 + k] = o;
        }
    } else {
        bf16x8 o0, o1;
#pragma unroll
        for (int j = 0; j < 8; ++j) {
            o0[j] = (short)f2bf(acc[j]);
            o1[j] = (short)f2bf(acc[8 + j]);
        }
        ((bf16x8*)out)[(size_t)node * 32 + ql * 2]     = o0;
        ((bf16x8*)out)[(size_t)node * 32 + ql * 2 + 1] = o1;
    }
}

extern "C" void kernel_launch(void* const* d_in, const int* in_sizes, int n_in,
                              void* d_out, int out_size, void* d_ws, size_t ws_size,
                              hipStream_t stream) {
    const float* x  = (const float*)d_in[0];
    const int* ei   = (const int*)d_in[1];
    const float* w1 = (const float*)d_in[2];
    const float* b1 = (const float*)d_in[3];
    const float* w2 = (const float*)d_in[4];
    const float* b2 = (const float*)d_in[5];
    const float* gw = (const float*)d_in[6];
    const float* gb = (const float*)d_in[7];

    const int N = NNODES, E = NEDGES;
    const int* src = ei;
    const int* dst = ei + E;

    // Workspace layout (~158 MB)
    char* p = (char*)d_ws;
    unsigned short* h1   = (unsigned short*)p; p += (size_t)MPAD * HDIM * 2;  // 51.2 MB
    unsigned short* h    = (unsigned short*)p; p += (size_t)MPAD * HDIM * 2;
    unsigned short* m    = (unsigned short*)p; p += (size_t)MPAD * HDIM * 2;
    unsigned short* w1t  = (unsigned short*)p; p += (size_t)FIN * HDIM * 2;
    unsigned short* gwt  = (unsigned short*)p; p += (size_t)NLAYERS * HDIM * HDIM * 2;
    unsigned short* w2c  = (unsigned short*)p; p += (size_t)HDIM * HDIM * 2;   // w2 bf16 row-major
    unsigned short* fBt  = (unsigned short*)p; p += (size_t)HDIM * HDIM * 2;   // folded W2*G0, Bt layout
    float* foldb = (float*)p;          p += (size_t)HDIM * 4;                  // folded bias b2*G0
    unsigned* cnt = (unsigned*)p;      p += (size_t)N * 4;
    float* dinv = (float*)p;           p += (size_t)N * 4;
    int* rs = (int*)p;                 p += (size_t)(N + 1) * 4 + 12;
    unsigned* blocksum = (unsigned*)p; p += 512 * 4;
    int2* edata = (int2*)p;            p += (size_t)E * 8;   // packed (src, weight)

    // xb: x converted to bf16 [MPAD][FIN] — reuses the idle m buffer (25.6 MB < 51.2 MB)
    unsigned short* xb = m;

    const int nb = (N + 255) / 256;             // 391
    const int MY = MPAD / 128;                  // 782 row-tiles
    const int ggrid = 16 * ((MY + 7) / 8);      // 1568 (pair-swizzled 1-D grid)

    // ---- Merged prep (conv x, wprep w1, wprep gw, conv w2, zero cnt, foldbias) ----
    prep_k<<<13852, 256, 0, stream>>>(x, xb, w1, w1t, gw, gwt, w2, w2c, b2, foldb, cnt);

    // ---- Fold: fBt[c][k'] = sum_j G0[j][c]*W2[k'][j]  (my=2 -> grid 16, 14 blocks idle)
    gemm_lds_k<HDIM, false, false><<<16, 256, 0, stream>>>(gwt, w2c, nullptr, fBt, 2);

    // ---- CSR build (4 launches) ----
    count_k<<<(E + 255) / 256, 256, 0, stream>>>(dst, cnt, E);
    scan1_k<<<nb, 256, 0, stream>>>(cnt, rs, blocksum, dinv, N);
    scan23_k<<<nb, 256, 0, stream>>>(rs, blocksum, N, E);
    fill_k<<<(E + 255) / 256, 256, 0, stream>>>(src, dst, rs, cnt, dinv, edata, E);

    // ---- Encoder GEMM1: h1 = relu(xb @ W1 + b1) ----
    gemm_lds_k<FIN, true, true><<<ggrid, 256, 0, stream>>>(xb, w1t, b1, h1, MY);

    // ---- Layer 0 (folded): m = h1 @ (W2*G0) + b2*G0  (overwrites xb — already consumed)
    gemm_lds_k<HDIM, true, false><<<ggrid, 256, 0, stream>>>(h1, fBt, foldb, m, MY);
    gather_k<false><<<N / 16, 256, 0, stream>>>(rs, edata, dinv, m, gb, h, N);

    // ---- Layers 1..2 ----
    for (int l = 1; l < NLAYERS; ++l) {
        const unsigned short* wl = gwt + (size_t)l * HDIM * HDIM;
        const float* bl = gb + (size_t)l * HDIM;
        gemm_lds_k<HDIM, false, false><<<ggrid, 256, 0, stream>>>(h, wl, nullptr, m, MY);
        if (l < NLAYERS - 1)
            gather_k<false><<<N / 16, 256, 0, stream>>>(rs, edata, dinv, m, bl, h, N);
        else
            gather_k<true><<<N / 16, 256, 0, stream>>>(rs, edata, dinv, m, bl, d_out, N);
    }
}

// Round 8
// 439.328 us; speedup vs baseline: 1.0081x; 1.0081x over previous
//
#include <hip/hip_runtime.h>
#include <hip/hip_bf16.h>

// Problem constants
#define NNODES 100000
#define NEDGES 300000
#define FIN 128
#define HDIM 256
#define NLAYERS 3
#define MPAD 100096  // 782 * 128 — all GEMMs compute exactly MPAD rows, no predicates

typedef float f32x4 __attribute__((ext_vector_type(4)));
typedef short bf16x8 __attribute__((ext_vector_type(8)));

__device__ inline float bf2f(unsigned short u) {
    union { unsigned int i; float f; } v;
    v.i = ((unsigned int)u) << 16;
    return v.f;
}
__device__ inline unsigned short f2bf(float f) {  // RNE
    union { float f; unsigned int i; } v;
    v.f = f;
    return (unsigned short)((v.i + 0x7fffu + ((v.i >> 16) & 1u)) >> 16);
}

// 16-byte async global->LDS (dest = wave-uniform base + lane*16)
__device__ __forceinline__ void gll16(const unsigned short* g, unsigned short* l) {
    __builtin_amdgcn_global_load_lds(
        (const __attribute__((address_space(1))) unsigned int*)g,
        (__attribute__((address_space(3))) unsigned int*)l, 16, 0, 0);
}

// ---------------------------------------------------------------------------
// Counted-vmcnt pipelined MFMA GEMM (R3 structure + R5 XCD pair-swizzle +
// swapped-operand epilogue).
// 128x128 tile, 4 waves, BK=32, TRIPLE-buffered LDS (48 KiB, 3 blocks/CU).
// Per K-step: vmcnt(4) -> s_barrier -> issue stage(t+2) -> ds_read buf[t%3]
// -> 16 MFMA.  (Race audit in R3 notes; unchanged.)
// XCD PAIR-SWIZZLE: 1-D grid, bid = 16t + 8x + u (u=0..7), y = 8t+u; the two
// col-tiles of row-panel y sit 8 apart -> same XCD, co-resident -> A L2-hits.
// SWAPPED OPERANDS: acc[i][j] = mfma(b[j], a[i], acc) gives D layout
// lane&15 = C-row, kq*4+reg = 4 CONSECUTIVE C-cols -> ushort4 epilogue
// (16x 8B stores/thread, each wave-store 16 rows x 32B contiguous).
// ---------------------------------------------------------------------------
template <int K, bool BIAS, bool RELU>
__global__ __launch_bounds__(256) void gemm_lds_k(
    const unsigned short* __restrict__ A, const unsigned short* __restrict__ Bt,
    const float* __restrict__ bias, unsigned short* __restrict__ C, int my) {
    constexpr int BK = 32;        // 64 B per LDS row
    constexpr int NT = K / BK;    // 4 (K=128) or 8 (K=256)
    __shared__ unsigned short sA[3][128 * BK];
    __shared__ unsigned short sB[3][128 * BK];

    const int bid   = blockIdx.x;
    const int ytile = (bid >> 4) * 8 + (bid & 7);
    if (ytile >= my) return;               // uniform whole-block exit, pre-barrier
    const int xcol  = (bid >> 3) & 1;
    const int rowblk = ytile * 128;
    const int colblk = xcol * 128;

    const int tid  = threadIdx.x;
    const int lane = tid & 63;
    const int wid  = tid >> 6;
    const int r15  = lane & 15;
    const int kq   = lane >> 4;        // 0..3
    const int wr   = wid >> 1;         // wave row-tile (0/1)
    const int wc   = wid & 1;          // wave col-tile (0/1)

    // Staging geometry: wave w, chunk q covers LDS rows [q*64 + w*16, +16),
    // each row = 64 B; lane L writes row (L>>2), phys slot (L&3).
    // Phys slot p at row r holds logical k-slot p ^ ((r>>1)&3)  (involution).
    const unsigned short* gA[2];
    const unsigned short* gB[2];
    int ldsbase[2];
#pragma unroll
    for (int q = 0; q < 2; ++q) {
        int rr   = q * 64 + wid * 16 + (lane >> 2);
        int slot = (lane & 3) ^ ((rr >> 1) & 3);
        gA[q] = A  + (size_t)(rowblk + rr) * K + slot * 8;
        gB[q] = Bt + (size_t)(colblk + rr) * K + slot * 8;
        ldsbase[q] = (q * 64 + wid * 16) * BK;   // wave-uniform
    }

    // Read-side swizzled fragment offsets (elements)
    const int sread = ((kq ^ ((r15 >> 1) & 3)) * 8);
    int aoff[4], boff[4];
#pragma unroll
    for (int i = 0; i < 4; ++i) {
        aoff[i] = (wr * 64 + i * 16 + r15) * BK + sread;
        boff[i] = (wc * 64 + i * 16 + r15) * BK + sread;
    }

    f32x4 acc[4][4] = {};

    // prologue: stage K-tiles 0 and 1 into bufs 0 and 1 (8 loads in flight)
#pragma unroll
    for (int q = 0; q < 2; ++q) {
        gll16(gA[q], &sA[0][ldsbase[q]]);
        gll16(gB[q], &sB[0][ldsbase[q]]);
    }
#pragma unroll
    for (int q = 0; q < 2; ++q) {
        gll16(gA[q] + BK, &sA[1][ldsbase[q]]);
        gll16(gB[q] + BK, &sB[1][ldsbase[q]]);
    }

#pragma unroll
    for (int t = 0; t < NT; ++t) {
        // counted drain: only stage(t) must have landed; stage(t+1) stays in flight
        if (t + 1 < NT) {
            asm volatile("s_waitcnt vmcnt(4)" ::: "memory");
        } else {
            asm volatile("s_waitcnt vmcnt(0)" ::: "memory");
        }
        __builtin_amdgcn_s_barrier();
        // issue stage(t+2) AFTER the barrier (its buffer's last readers were
        // iter t-1, all retired before any wave passed this barrier)
        if (t + 2 < NT) {
#pragma unroll
            for (int q = 0; q < 2; ++q) {
                gll16(gA[q] + (t + 2) * BK, &sA[(t + 2) % 3][ldsbase[q]]);
                gll16(gB[q] + (t + 2) * BK, &sB[(t + 2) % 3][ldsbase[q]]);
            }
        }
        bf16x8 a[4], b[4];
#pragma unroll
        for (int i = 0; i < 4; ++i) a[i] = *(const bf16x8*)&sA[t % 3][aoff[i]];
#pragma unroll
        for (int j = 0; j < 4; ++j) b[j] = *(const bf16x8*)&sB[t % 3][boff[j]];
        // swapped operands: lane&15 = C-row, kq*4+reg = C-col
#pragma unroll
        for (int i = 0; i < 4; ++i)
#pragma unroll
            for (int j = 0; j < 4; ++j)
                acc[i][j] = __builtin_amdgcn_mfma_f32_16x16x32_bf16(b[j], a[i], acc[i][j], 0, 0, 0);
    }

    // Epilogue: lane holds C[row][colb..colb+3] per frag — one 8B store each
#pragma unroll
    for (int i = 0; i < 4; ++i) {
        int row = rowblk + wr * 64 + i * 16 + r15;
#pragma unroll
        for (int j = 0; j < 4; ++j) {
            int colb = colblk + wc * 64 + j * 16 + kq * 4;
            float v0 = acc[i][j][0], v1 = acc[i][j][1], v2 = acc[i][j][2], v3 = acc[i][j][3];
            if (BIAS) {
                float4 bb = ((const float4*)bias)[colb >> 2];
                v0 += bb.x; v1 += bb.y; v2 += bb.z; v3 += bb.w;
            }
            if (RELU) {
                v0 = fmaxf(v0, 0.0f); v1 = fmaxf(v1, 0.0f);
                v2 = fmaxf(v2, 0.0f); v3 = fmaxf(v3, 0.0f);
            }
            ushort4 o;
            o.x = f2bf(v0); o.y = f2bf(v1); o.z = f2bf(v2); o.w = f2bf(v3);
            *(ushort4*)&C[(size_t)row * HDIM + colb] = o;
        }
    }
}

// ---------------------------------------------------------------------------
// Merged prep kernel, partitioned by blockIdx over 6 independent jobs:
//   [0,12500):      conv x -> xb   (fp32->bf16, x4)   [N*FIN/4 = 3.2M items]
//   [12500,12628):  wprep w1 -> w1t  (transpose+convert, K=FIN)
//   [12628,13396):  wprep gw -> gwt  (3 mats, K=HDIM)
//   [13396,13460):  conv w2 -> w2c
//   [13460,13851):  zero cnt (NNODES)
//   [13851]:        foldbias fb[c] = sum_j b2[j]*G0[j][c]
// ---------------------------------------------------------------------------
__global__ __launch_bounds__(256) void prep_k(
    const float* __restrict__ x, unsigned short* __restrict__ xb,
    const float* __restrict__ w1, unsigned short* __restrict__ w1t,
    const float* __restrict__ gw, unsigned short* __restrict__ gwt,
    const float* __restrict__ w2, unsigned short* __restrict__ w2c,
    const float* __restrict__ b2, float* __restrict__ foldb,
    unsigned* __restrict__ cnt) {
    int b = blockIdx.x;
    int tid = threadIdx.x;
    if (b < 12500) {                     // conv x (x4)
        int i = b * 256 + tid;           // < 3,200,000
        float4 v = ((const float4*)x)[i];
        ushort4 u;
        u.x = f2bf(v.x); u.y = f2bf(v.y); u.z = f2bf(v.z); u.w = f2bf(v.w);
        ((ushort4*)xb)[i] = u;
    } else if (b < 12628) {              // wprep w1: [FIN][256] -> [256][FIN]
        int i = (b - 12500) * 256 + tid; // < 32768
        int k = i >> 8, p = i & 255;
        w1t[(size_t)p * FIN + k] = f2bf(w1[i]);
    } else if (b < 13396) {              // wprep gw: [3][256][256] -> transposed
        int i = (b - 12628) * 256 + tid; // < 196608
        int mat = i >> 16;
        int r = i & 65535;
        int k = r >> 8, p = r & 255;
        gwt[(size_t)mat * 65536 + (size_t)p * HDIM + k] = f2bf(gw[i]);
    } else if (b < 13460) {              // conv w2 (x4): 16384 float4s
        int i = (b - 13396) * 256 + tid;
        float4 v = ((const float4*)w2)[i];
        ushort4 u;
        u.x = f2bf(v.x); u.y = f2bf(v.y); u.z = f2bf(v.z); u.w = f2bf(v.w);
        ((ushort4*)w2c)[i] = u;
    } else if (b < 13851) {              // zero cnt
        int i = (b - 13460) * 256 + tid;
        if (i < NNODES) cnt[i] = 0u;
    } else {                             // foldbias (one block)
        int c = tid;
        float s = 0.0f;
#pragma unroll 8
        for (int j = 0; j < HDIM; ++j) s += b2[j] * gw[(size_t)j * HDIM + c];
        foldb[c] = s;
    }
}

// ---------------------------------------------------------------------------
// CSR build utilities
// ---------------------------------------------------------------------------
__global__ void count_k(const int* __restrict__ dst, unsigned* __restrict__ cnt, int E) {
    int e = blockIdx.x * blockDim.x + threadIdx.x;
    if (e < E) atomicAdd(&cnt[dst[e]], 1u);
}

// scan1 also computes dinv and zeroes cnt (cursor reuse)
__global__ __launch_bounds__(256) void scan1_k(unsigned* __restrict__ cnt,
                                               int* __restrict__ rs,
                                               unsigned* __restrict__ blocksum,
                                               float* __restrict__ dinv, int N) {
    __shared__ unsigned tmp[256];
    int tid = threadIdx.x;
    int gid = blockIdx.x * 256 + tid;
    unsigned v = (gid < N) ? cnt[gid] : 0u;
    if (gid < N) {
        dinv[gid] = 1.0f / sqrtf((float)(v + 1u));  // +1 = self loop
        cnt[gid] = 0u;                               // reset for cursor use
    }
    tmp[tid] = v;
    __syncthreads();
#pragma unroll
    for (int off = 1; off < 256; off <<= 1) {
        unsigned t = (tid >= off) ? tmp[tid - off] : 0u;
        __syncthreads();
        tmp[tid] += t;
        __syncthreads();
    }
    if (gid < N) rs[gid] = (int)(tmp[tid] - v);
    if (tid == 255) blocksum[blockIdx.x] = tmp[tid];
}

// scan23: merged scan2+scan3. Each block b reduces the RAW per-block totals
// blocksum[0..b) itself (<=391 values, strided loads + block reduce), then
// adds that prefix to its rs slice.  Saves one launch.
__global__ __launch_bounds__(256) void scan23_k(int* __restrict__ rs,
                                                const unsigned* __restrict__ blocksum,
                                                int N, int E) {
    const int b = blockIdx.x, tid = threadIdx.x;
    unsigned s = 0;
    for (int i = tid; i < b; i += 256) s += blocksum[i];
    __shared__ unsigned red[4];
#pragma unroll
    for (int off = 32; off > 0; off >>= 1) s += __shfl_down(s, off);
    if ((tid & 63) == 0) red[tid >> 6] = s;
    __syncthreads();
    unsigned pref = red[0] + red[1] + red[2] + red[3];
    int gid = b * 256 + tid;
    if (gid < N) rs[gid] += (int)pref;
    if (gid == N) rs[N] = E;
}

// fill_k packs (src, weight) into one int2 per edge — single 8B load in gather
__global__ void fill_k(const int* __restrict__ src, const int* __restrict__ dst,
                       const int* __restrict__ rs, unsigned* __restrict__ cursor,
                       const float* __restrict__ dinv,
                       int2* __restrict__ edata, int E) {
    int e = blockIdx.x * blockDim.x + threadIdx.x;
    if (e >= E) return;
    int s = src[e], d = dst[e];
    int pos = rs[d] + (int)atomicAdd(&cursor[d], 1u);
    float w = dinv[s] * dinv[d];
    edata[pos] = make_int2(s, __float_as_int(w));
}

// ---------------------------------------------------------------------------
// CSR gather-aggregate (bf16 m), fused self-loop + bias + ReLU.
// TWO nodes per wave (R6 version — best measured): half-wave (32 lanes x
// ushort8 = 512B) per node row.  12500 blocks, 8 nodes/block.
// Cooperative half-wave edge-metadata load + half-wave shuffle broadcast +
// 4-wide unrolled independent row gathers. Masked slots carry (s=0, w=0.0).
// ---------------------------------------------------------------------------
template <bool OUTF32>
__global__ __launch_bounds__(256) void gather_k(const int* __restrict__ rs,
                                                const int2* __restrict__ edata,
                                                const float* __restrict__ dinv,
                                                const unsigned short* __restrict__ m,
                                                const float* __restrict__ bias,
                                                void* __restrict__ out, int N) {
    const int wid  = threadIdx.x >> 6;   // 0..3
    const int lane = threadIdx.x & 63;
    const int half = lane >> 5;          // 0/1: which node of the pair
    const int hl   = lane & 31;          // lane within half
    const int node = blockIdx.x * 8 + wid * 2 + half;

    const int beg = rs[node], end = rs[node + 1];
    const float d = dinv[node];
    const float w0 = d * d;

    // self row: 32 lanes x ushort8 = 512B
    bf16x8 u = ((const bf16x8*)(m + (size_t)node * HDIM))[hl];
    float acc[8];
#pragma unroll
    for (int j = 0; j < 8; ++j) acc[j] = bf2f((unsigned short)u[j]) * w0;

    for (int base = beg; base < end; base += 32) {
        int2 ed = (base + hl < end) ? edata[base + hl] : make_int2(0, 0);
        int take = end - base;
        if (take > 32) take = 32;
        for (int e = 0; e < take; e += 4) {
            // broadcast from this half's metadata lanes
            int s0 = __shfl(ed.x, half * 32 + e + 0);
            int s1 = __shfl(ed.x, half * 32 + e + 1);
            int s2 = __shfl(ed.x, half * 32 + e + 2);
            int s3 = __shfl(ed.x, half * 32 + e + 3);
            float wq0 = __int_as_float(__shfl(ed.y, half * 32 + e + 0));
            float wq1 = __int_as_float(__shfl(ed.y, half * 32 + e + 1));
            float wq2 = __int_as_float(__shfl(ed.y, half * 32 + e + 2));
            float wq3 = __int_as_float(__shfl(ed.y, half * 32 + e + 3));
            bf16x8 v0 = ((const bf16x8*)(m + (size_t)s0 * HDIM))[hl];
            bf16x8 v1 = ((const bf16x8*)(m + (size_t)s1 * HDIM))[hl];
            bf16x8 v2 = ((const bf16x8*)(m + (size_t)s2 * HDIM))[hl];
            bf16x8 v3 = ((const bf16x8*)(m + (size_t)s3 * HDIM))[hl];
#pragma unroll
            for (int j = 0; j < 8; ++j) {
                acc[j] += bf2f((unsigned short)v0[j]) * wq0;
                acc[j] += bf2f((unsigned short)v1[j]) * wq1;
                acc[j] += bf2f((unsigned short)v2[j]) * wq2;
                acc[j] += bf2f((unsigned short)v3[j]) * wq3;
            }
        }
    }

    // bias + ReLU on 8 cols (hl*8 .. hl*8+7)
    float4 b0 = ((const float4*)bias)[hl * 2];
    float4 b1 = ((const float4*)bias)[hl * 2 + 1];
    acc[0] = fmaxf(acc[0] + b0.x, 0.0f); acc[1] = fmaxf(acc[1] + b0.y, 0.0f);
    acc[2] = fmaxf(acc[2] + b0.z, 0.0f); acc[3] = fmaxf(acc[3] + b0.w, 0.0f);
    acc[4] = fmaxf(acc[4] + b1.x, 0.0f); acc[5] = fmaxf(acc[5] + b1.y, 0.0f);
    acc[6] = fmaxf(acc[6] + b1.z, 0.0f); acc[7] = fmaxf(acc[7] + b1.w, 0.0f);

    if (OUTF32) {
        float4 o0 = {acc[0], acc[1], acc[2], acc[3]};
        float4 o1 = {acc[4], acc[5], acc[6], acc[7]};
        ((float4*)out)[(size_t)node * 64 + hl * 2] = o0;
        ((float4*)out)[(size_t)node * 64 + hl * 2 + 1] = o1;
    } else {
        bf16x8 o;
#pragma unroll
        for (int j = 0; j < 8; ++j) o[j] = (short)f2bf(acc[j]);
        ((bf16x8*)out)[(size_t)node * 32 + hl] = o;
    }
}

extern "C" void kernel_launch(void* const* d_in, const int* in_sizes, int n_in,
                              void* d_out, int out_size, void* d_ws, size_t ws_size,
                              hipStream_t stream) {
    const float* x  = (const float*)d_in[0];
    const int* ei   = (const int*)d_in[1];
    const float* w1 = (const float*)d_in[2];
    const float* b1 = (const float*)d_in[3];
    const float* w2 = (const float*)d_in[4];
    const float* b2 = (const float*)d_in[5];
    const float* gw = (const float*)d_in[6];
    const float* gb = (const float*)d_in[7];

    const int N = NNODES, E = NEDGES;
    const int* src = ei;
    const int* dst = ei + E;

    // Workspace layout (~158 MB)
    char* p = (char*)d_ws;
    unsigned short* h1   = (unsigned short*)p; p += (size_t)MPAD * HDIM * 2;  // 51.2 MB
    unsigned short* h    = (unsigned short*)p; p += (size_t)MPAD * HDIM * 2;
    unsigned short* m    = (unsigned short*)p; p += (size_t)MPAD * HDIM * 2;
    unsigned short* w1t  = (unsigned short*)p; p += (size_t)FIN * HDIM * 2;
    unsigned short* gwt  = (unsigned short*)p; p += (size_t)NLAYERS * HDIM * HDIM * 2;
    unsigned short* w2c  = (unsigned short*)p; p += (size_t)HDIM * HDIM * 2;   // w2 bf16 row-major
    unsigned short* fBt  = (unsigned short*)p; p += (size_t)HDIM * HDIM * 2;   // folded W2*G0, Bt layout
    float* foldb = (float*)p;          p += (size_t)HDIM * 4;                  // folded bias b2*G0
    unsigned* cnt = (unsigned*)p;      p += (size_t)N * 4;
    float* dinv = (float*)p;           p += (size_t)N * 4;
    int* rs = (int*)p;                 p += (size_t)(N + 1) * 4 + 12;
    unsigned* blocksum = (unsigned*)p; p += 512 * 4;
    int2* edata = (int2*)p;            p += (size_t)E * 8;   // packed (src, weight)

    // xb: x converted to bf16 [MPAD][FIN] — reuses the idle m buffer (25.6 MB < 51.2 MB)
    unsigned short* xb = m;

    const int nb = (N + 255) / 256;             // 391
    const int MY = MPAD / 128;                  // 782 row-tiles
    const int ggrid = 16 * ((MY + 7) / 8);      // 1568 (pair-swizzled 1-D grid)

    // ---- Merged prep (conv x, wprep w1, wprep gw, conv w2, zero cnt, foldbias) ----
    prep_k<<<13852, 256, 0, stream>>>(x, xb, w1, w1t, gw, gwt, w2, w2c, b2, foldb, cnt);

    // ---- Fold: fBt[c][k'] = sum_j G0[j][c]*W2[k'][j]  (my=2 -> grid 16, 14 blocks idle)
    gemm_lds_k<HDIM, false, false><<<16, 256, 0, stream>>>(gwt, w2c, nullptr, fBt, 2);

    // ---- CSR build (4 launches) ----
    count_k<<<(E + 255) / 256, 256, 0, stream>>>(dst, cnt, E);
    scan1_k<<<nb, 256, 0, stream>>>(cnt, rs, blocksum, dinv, N);
    scan23_k<<<nb, 256, 0, stream>>>(rs, blocksum, N, E);
    fill_k<<<(E + 255) / 256, 256, 0, stream>>>(src, dst, rs, cnt, dinv, edata, E);

    // ---- Encoder GEMM1: h1 = relu(xb @ W1 + b1) ----
    gemm_lds_k<FIN, true, true><<<ggrid, 256, 0, stream>>>(xb, w1t, b1, h1, MY);

    // ---- Layer 0 (folded): m = h1 @ (W2*G0) + b2*G0  (overwrites xb — already consumed)
    gemm_lds_k<HDIM, true, false><<<ggrid, 256, 0, stream>>>(h1, fBt, foldb, m, MY);
    gather_k<false><<<N / 8, 256, 0, stream>>>(rs, edata, dinv, m, gb, h, N);

    // ---- Layers 1..2 ----
    for (int l = 1; l < NLAYERS; ++l) {
        const unsigned short* wl = gwt + (size_t)l * HDIM * HDIM;
        const float* bl = gb + (size_t)l * HDIM;
        gemm_lds_k<HDIM, false, false><<<ggrid, 256, 0, stream>>>(h, wl, nullptr, m, MY);
        if (l < NLAYERS - 1)
            gather_k<false><<<N / 8, 256, 0, stream>>>(rs, edata, dinv, m, bl, h, N);
        else
            gather_k<true><<<N / 8, 256, 0, stream>>>(rs, edata, dinv, m, bl, d_out, N);
    }
}

// Round 10
// 417.965 us; speedup vs baseline: 1.0596x; 1.0511x over previous
//
#include <hip/hip_runtime.h>
#include <hip/hip_bf16.h>

// Problem constants
#define NNODES 100000
#define NEDGES 300000
#define FIN 128
#define HDIM 256
#define NLAYERS 3
#define MPAD 100096  // 782 * 128 — all GEMMs compute exactly MPAD rows, no predicates

typedef float f32x4 __attribute__((ext_vector_type(4)));
typedef short bf16x8 __attribute__((ext_vector_type(8)));

__device__ inline float bf2f(unsigned short u) {
    union { unsigned int i; float f; } v;
    v.i = ((unsigned int)u) << 16;
    return v.f;
}
__device__ inline unsigned short f2bf(float f) {  // RNE
    union { float f; unsigned int i; } v;
    v.f = f;
    return (unsigned short)((v.i + 0x7fffu + ((v.i >> 16) & 1u)) >> 16);
}

// 16-byte async global->LDS (dest = wave-uniform base + lane*16)
__device__ __forceinline__ void gll16(const unsigned short* g, unsigned short* l) {
    __builtin_amdgcn_global_load_lds(
        (const __attribute__((address_space(1))) unsigned int*)g,
        (__attribute__((address_space(3))) unsigned int*)l, 16, 0, 0);
}

// ---------------------------------------------------------------------------
// Counted-vmcnt pipelined MFMA GEMM — EXACT R6 version (421.6 µs ledger).
// 128x128 tile, 4 waves, BK=32, TRIPLE-buffered LDS (48 KiB, 3 blocks/CU).
// Per K-step: vmcnt(4) -> s_barrier -> issue stage(t+2) -> ds_read buf[t%3]
// -> 16 MFMA (original operand order mfma(a,b)).
// XCD PAIR-SWIZZLE: 1-D grid, bid = 16t + 8x + u (u=0..7), y = 8t+u.
// Epilogue: original scalar 2B stores (col = lane&15-contiguous per 16-lane
// group).  NOTE: swapped-operand ushort4 epilogue REGRESSED +15us (R7/R8) —
// do not reintroduce without isolated counter evidence.
// ---------------------------------------------------------------------------
template <int K, bool BIAS, bool RELU>
__global__ __launch_bounds__(256) void gemm_lds_k(
    const unsigned short* __restrict__ A, const unsigned short* __restrict__ Bt,
    const float* __restrict__ bias, unsigned short* __restrict__ C, int my) {
    constexpr int BK = 32;        // 64 B per LDS row
    constexpr int NT = K / BK;    // 4 (K=128) or 8 (K=256)
    __shared__ unsigned short sA[3][128 * BK];
    __shared__ unsigned short sB[3][128 * BK];

    const int bid   = blockIdx.x;
    const int ytile = (bid >> 4) * 8 + (bid & 7);
    if (ytile >= my) return;               // uniform whole-block exit, pre-barrier
    const int xcol  = (bid >> 3) & 1;
    const int rowblk = ytile * 128;
    const int colblk = xcol * 128;

    const int tid  = threadIdx.x;
    const int lane = tid & 63;
    const int wid  = tid >> 6;
    const int r15  = lane & 15;
    const int kq   = lane >> 4;        // 0..3
    const int wr   = wid >> 1;         // wave row-tile (0/1)
    const int wc   = wid & 1;          // wave col-tile (0/1)

    // Staging geometry: wave w, chunk q covers LDS rows [q*64 + w*16, +16),
    // each row = 64 B; lane L writes row (L>>2), phys slot (L&3).
    // Phys slot p at row r holds logical k-slot p ^ ((r>>1)&3)  (involution).
    const unsigned short* gA[2];
    const unsigned short* gB[2];
    int ldsbase[2];
#pragma unroll
    for (int q = 0; q < 2; ++q) {
        int rr   = q * 64 + wid * 16 + (lane >> 2);
        int slot = (lane & 3) ^ ((rr >> 1) & 3);
        gA[q] = A  + (size_t)(rowblk + rr) * K + slot * 8;
        gB[q] = Bt + (size_t)(colblk + rr) * K + slot * 8;
        ldsbase[q] = (q * 64 + wid * 16) * BK;   // wave-uniform
    }

    // Read-side swizzled fragment offsets (elements)
    const int sread = ((kq ^ ((r15 >> 1) & 3)) * 8);
    int aoff[4], boff[4];
#pragma unroll
    for (int i = 0; i < 4; ++i) {
        aoff[i] = (wr * 64 + i * 16 + r15) * BK + sread;
        boff[i] = (wc * 64 + i * 16 + r15) * BK + sread;
    }

    f32x4 acc[4][4] = {};

    // prologue: stage K-tiles 0 and 1 into bufs 0 and 1 (8 loads in flight)
#pragma unroll
    for (int q = 0; q < 2; ++q) {
        gll16(gA[q], &sA[0][ldsbase[q]]);
        gll16(gB[q], &sB[0][ldsbase[q]]);
    }
#pragma unroll
    for (int q = 0; q < 2; ++q) {
        gll16(gA[q] + BK, &sA[1][ldsbase[q]]);
        gll16(gB[q] + BK, &sB[1][ldsbase[q]]);
    }

#pragma unroll
    for (int t = 0; t < NT; ++t) {
        // counted drain: only stage(t) must have landed; stage(t+1) stays in flight
        if (t + 1 < NT) {
            asm volatile("s_waitcnt vmcnt(4)" ::: "memory");
        } else {
            asm volatile("s_waitcnt vmcnt(0)" ::: "memory");
        }
        __builtin_amdgcn_s_barrier();
        // issue stage(t+2) AFTER the barrier (its buffer's last readers were
        // iter t-1, all retired before any wave passed this barrier)
        if (t + 2 < NT) {
#pragma unroll
            for (int q = 0; q < 2; ++q) {
                gll16(gA[q] + (t + 2) * BK, &sA[(t + 2) % 3][ldsbase[q]]);
                gll16(gB[q] + (t + 2) * BK, &sB[(t + 2) % 3][ldsbase[q]]);
            }
        }
        bf16x8 a[4], b[4];
#pragma unroll
        for (int i = 0; i < 4; ++i) a[i] = *(const bf16x8*)&sA[t % 3][aoff[i]];
#pragma unroll
        for (int j = 0; j < 4; ++j) b[j] = *(const bf16x8*)&sB[t % 3][boff[j]];
#pragma unroll
        for (int i = 0; i < 4; ++i)
#pragma unroll
            for (int j = 0; j < 4; ++j)
                acc[i][j] = __builtin_amdgcn_mfma_f32_16x16x32_bf16(a[i], b[j], acc[i][j], 0, 0, 0);
    }

    // Epilogue: C/D layout col = lane&15, row = (lane>>4)*4 + reg
#pragma unroll
    for (int i = 0; i < 4; ++i) {
#pragma unroll
        for (int reg = 0; reg < 4; ++reg) {
            int row = rowblk + wr * 64 + i * 16 + kq * 4 + reg;
#pragma unroll
            for (int j = 0; j < 4; ++j) {
                int col = colblk + wc * 64 + j * 16 + r15;
                float v = acc[i][j][reg];
                if (BIAS) v += bias[col];
                if (RELU) v = fmaxf(v, 0.0f);
                C[(size_t)row * HDIM + col] = f2bf(v);
            }
        }
    }
}

// ---------------------------------------------------------------------------
// Merged prep kernel, partitioned by blockIdx over 6 independent jobs:
//   [0,12500):      conv x -> xb   (fp32->bf16, x4)   [N*FIN/4 = 3.2M items]
//   [12500,12628):  wprep w1 -> w1t  (transpose+convert, K=FIN)
//   [12628,13396):  wprep gw -> gwt  (3 mats, K=HDIM)
//   [13396,13460):  conv w2 -> w2c
//   [13460,13851):  zero cnt (NNODES)
//   [13851]:        foldbias fb[c] = sum_j b2[j]*G0[j][c]
// ---------------------------------------------------------------------------
__global__ __launch_bounds__(256) void prep_k(
    const float* __restrict__ x, unsigned short* __restrict__ xb,
    const float* __restrict__ w1, unsigned short* __restrict__ w1t,
    const float* __restrict__ gw, unsigned short* __restrict__ gwt,
    const float* __restrict__ w2, unsigned short* __restrict__ w2c,
    const float* __restrict__ b2, float* __restrict__ foldb,
    unsigned* __restrict__ cnt) {
    int b = blockIdx.x;
    int tid = threadIdx.x;
    if (b < 12500) {                     // conv x (x4)
        int i = b * 256 + tid;           // < 3,200,000
        float4 v = ((const float4*)x)[i];
        ushort4 u;
        u.x = f2bf(v.x); u.y = f2bf(v.y); u.z = f2bf(v.z); u.w = f2bf(v.w);
        ((ushort4*)xb)[i] = u;
    } else if (b < 12628) {              // wprep w1: [FIN][256] -> [256][FIN]
        int i = (b - 12500) * 256 + tid; // < 32768
        int k = i >> 8, p = i & 255;
        w1t[(size_t)p * FIN + k] = f2bf(w1[i]);
    } else if (b < 13396) {              // wprep gw: [3][256][256] -> transposed
        int i = (b - 12628) * 256 + tid; // < 196608
        int mat = i >> 16;
        int r = i & 65535;
        int k = r >> 8, p = r & 255;
        gwt[(size_t)mat * 65536 + (size_t)p * HDIM + k] = f2bf(gw[i]);
    } else if (b < 13460) {              // conv w2 (x4): 16384 float4s
        int i = (b - 13396) * 256 + tid;
        float4 v = ((const float4*)w2)[i];
        ushort4 u;
        u.x = f2bf(v.x); u.y = f2bf(v.y); u.z = f2bf(v.z); u.w = f2bf(v.w);
        ((ushort4*)w2c)[i] = u;
    } else if (b < 13851) {              // zero cnt
        int i = (b - 13460) * 256 + tid;
        if (i < NNODES) cnt[i] = 0u;
    } else {                             // foldbias (one block)
        int c = tid;
        float s = 0.0f;
#pragma unroll 8
        for (int j = 0; j < HDIM; ++j) s += b2[j] * gw[(size_t)j * HDIM + c];
        foldb[c] = s;
    }
}

// ---------------------------------------------------------------------------
// CSR build utilities
// ---------------------------------------------------------------------------
__global__ void count_k(const int* __restrict__ dst, unsigned* __restrict__ cnt, int E) {
    int e = blockIdx.x * blockDim.x + threadIdx.x;
    if (e < E) atomicAdd(&cnt[dst[e]], 1u);
}

// scan1 also computes dinv and zeroes cnt (cursor reuse)
__global__ __launch_bounds__(256) void scan1_k(unsigned* __restrict__ cnt,
                                               int* __restrict__ rs,
                                               unsigned* __restrict__ blocksum,
                                               float* __restrict__ dinv, int N) {
    __shared__ unsigned tmp[256];
    int tid = threadIdx.x;
    int gid = blockIdx.x * 256 + tid;
    unsigned v = (gid < N) ? cnt[gid] : 0u;
    if (gid < N) {
        dinv[gid] = 1.0f / sqrtf((float)(v + 1u));  // +1 = self loop
        cnt[gid] = 0u;                               // reset for cursor use
    }
    tmp[tid] = v;
    __syncthreads();
#pragma unroll
    for (int off = 1; off < 256; off <<= 1) {
        unsigned t = (tid >= off) ? tmp[tid - off] : 0u;
        __syncthreads();
        tmp[tid] += t;
        __syncthreads();
    }
    if (gid < N) rs[gid] = (int)(tmp[tid] - v);
    if (tid == 255) blocksum[blockIdx.x] = tmp[tid];
}

// scan23: merged scan2+scan3. Each block b reduces the RAW per-block totals
// blocksum[0..b) itself (<=391 values, strided loads + block reduce), then
// adds that prefix to its rs slice.  Saves one launch.
__global__ __launch_bounds__(256) void scan23_k(int* __restrict__ rs,
                                                const unsigned* __restrict__ blocksum,
                                                int N, int E) {
    const int b = blockIdx.x, tid = threadIdx.x;
    unsigned s = 0;
    for (int i = tid; i < b; i += 256) s += blocksum[i];
    __shared__ unsigned red[4];
#pragma unroll
    for (int off = 32; off > 0; off >>= 1) s += __shfl_down(s, off);
    if ((tid & 63) == 0) red[tid >> 6] = s;
    __syncthreads();
    unsigned pref = red[0] + red[1] + red[2] + red[3];
    int gid = b * 256 + tid;
    if (gid < N) rs[gid] += (int)pref;
    if (gid == N) rs[N] = E;
}

// fill_k packs (src, weight) into one int2 per edge — single 8B load in gather
__global__ void fill_k(const int* __restrict__ src, const int* __restrict__ dst,
                       const int* __restrict__ rs, unsigned* __restrict__ cursor,
                       const float* __restrict__ dinv,
                       int2* __restrict__ edata, int E) {
    int e = blockIdx.x * blockDim.x + threadIdx.x;
    if (e >= E) return;
    int s = src[e], d = dst[e];
    int pos = rs[d] + (int)atomicAdd(&cursor[d], 1u);
    float w = dinv[s] * dinv[d];
    edata[pos] = make_int2(s, __float_as_int(w));
}

// ---------------------------------------------------------------------------
// CSR gather-aggregate (bf16 m), fused self-loop + bias + ReLU.
// TWO nodes per wave (R6 version — best measured): half-wave (32 lanes x
// ushort8 = 512B) per node row.  12500 blocks, 8 nodes/block.
// Cooperative half-wave edge-metadata load + half-wave shuffle broadcast +
// 4-wide unrolled independent row gathers. Masked slots carry (s=0, w=0.0).
// ---------------------------------------------------------------------------
template <bool OUTF32>
__global__ __launch_bounds__(256) void gather_k(const int* __restrict__ rs,
                                                const int2* __restrict__ edata,
                                                const float* __restrict__ dinv,
                                                const unsigned short* __restrict__ m,
                                                const float* __restrict__ bias,
                                                void* __restrict__ out, int N) {
    const int wid  = threadIdx.x >> 6;   // 0..3
    const int lane = threadIdx.x & 63;
    const int half = lane >> 5;          // 0/1: which node of the pair
    const int hl   = lane & 31;          // lane within half
    const int node = blockIdx.x * 8 + wid * 2 + half;

    const int beg = rs[node], end = rs[node + 1];
    const float d = dinv[node];
    const float w0 = d * d;

    // self row: 32 lanes x ushort8 = 512B
    bf16x8 u = ((const bf16x8*)(m + (size_t)node * HDIM))[hl];
    float acc[8];
#pragma unroll
    for (int j = 0; j < 8; ++j) acc[j] = bf2f((unsigned short)u[j]) * w0;

    for (int base = beg; base < end; base += 32) {
        int2 ed = (base + hl < end) ? edata[base + hl] : make_int2(0, 0);
        int take = end - base;
        if (take > 32) take = 32;
        for (int e = 0; e < take; e += 4) {
            // broadcast from this half's metadata lanes
            int s0 = __shfl(ed.x, half * 32 + e + 0);
            int s1 = __shfl(ed.x, half * 32 + e + 1);
            int s2 = __shfl(ed.x, half * 32 + e + 2);
            int s3 = __shfl(ed.x, half * 32 + e + 3);
            float wq0 = __int_as_float(__shfl(ed.y, half * 32 + e + 0));
            float wq1 = __int_as_float(__shfl(ed.y, half * 32 + e + 1));
            float wq2 = __int_as_float(__shfl(ed.y, half * 32 + e + 2));
            float wq3 = __int_as_float(__shfl(ed.y, half * 32 + e + 3));
            bf16x8 v0 = ((const bf16x8*)(m + (size_t)s0 * HDIM))[hl];
            bf16x8 v1 = ((const bf16x8*)(m + (size_t)s1 * HDIM))[hl];
            bf16x8 v2 = ((const bf16x8*)(m + (size_t)s2 * HDIM))[hl];
            bf16x8 v3 = ((const bf16x8*)(m + (size_t)s3 * HDIM))[hl];
#pragma unroll
            for (int j = 0; j < 8; ++j) {
                acc[j] += bf2f((unsigned short)v0[j]) * wq0;
                acc[j] += bf2f((unsigned short)v1[j]) * wq1;
                acc[j] += bf2f((unsigned short)v2[j]) * wq2;
                acc[j] += bf2f((unsigned short)v3[j]) * wq3;
            }
        }
    }

    // bias + ReLU on 8 cols (hl*8 .. hl*8+7)
    float4 b0 = ((const float4*)bias)[hl * 2];
    float4 b1 = ((const float4*)bias)[hl * 2 + 1];
    acc[0] = fmaxf(acc[0] + b0.x, 0.0f); acc[1] = fmaxf(acc[1] + b0.y, 0.0f);
    acc[2] = fmaxf(acc[2] + b0.z, 0.0f); acc[3] = fmaxf(acc[3] + b0.w, 0.0f);
    acc[4] = fmaxf(acc[4] + b1.x, 0.0f); acc[5] = fmaxf(acc[5] + b1.y, 0.0f);
    acc[6] = fmaxf(acc[6] + b1.z, 0.0f); acc[7] = fmaxf(acc[7] + b1.w, 0.0f);

    if (OUTF32) {
        float4 o0 = {acc[0], acc[1], acc[2], acc[3]};
        float4 o1 = {acc[4], acc[5], acc[6], acc[7]};
        ((float4*)out)[(size_t)node * 64 + hl * 2] = o0;
        ((float4*)out)[(size_t)node * 64 + hl * 2 + 1] = o1;
    } else {
        bf16x8 o;
#pragma unroll
        for (int j = 0; j < 8; ++j) o[j] = (short)f2bf(acc[j]);
        ((bf16x8*)out)[(size_t)node * 32 + hl] = o;
    }
}

extern "C" void kernel_launch(void* const* d_in, const int* in_sizes, int n_in,
                              void* d_out, int out_size, void* d_ws, size_t ws_size,
                              hipStream_t stream) {
    const float* x  = (const float*)d_in[0];
    const int* ei   = (const int*)d_in[1];
    const float* w1 = (const float*)d_in[2];
    const float* b1 = (const float*)d_in[3];
    const float* w2 = (const float*)d_in[4];
    const float* b2 = (const float*)d_in[5];
    const float* gw = (const float*)d_in[6];
    const float* gb = (const float*)d_in[7];

    const int N = NNODES, E = NEDGES;
    const int* src = ei;
    const int* dst = ei + E;

    // Workspace layout (~158 MB)
    char* p = (char*)d_ws;
    unsigned short* h1   = (unsigned short*)p; p += (size_t)MPAD * HDIM * 2;  // 51.2 MB
    unsigned short* h    = (unsigned short*)p; p += (size_t)MPAD * HDIM * 2;
    unsigned short* m    = (unsigned short*)p; p += (size_t)MPAD * HDIM * 2;
    unsigned short* w1t  = (unsigned short*)p; p += (size_t)FIN * HDIM * 2;
    unsigned short* gwt  = (unsigned short*)p; p += (size_t)NLAYERS * HDIM * HDIM * 2;
    unsigned short* w2c  = (unsigned short*)p; p += (size_t)HDIM * HDIM * 2;   // w2 bf16 row-major
    unsigned short* fBt  = (unsigned short*)p; p += (size_t)HDIM * HDIM * 2;   // folded W2*G0, Bt layout
    float* foldb = (float*)p;          p += (size_t)HDIM * 4;                  // folded bias b2*G0
    unsigned* cnt = (unsigned*)p;      p += (size_t)N * 4;
    float* dinv = (float*)p;           p += (size_t)N * 4;
    int* rs = (int*)p;                 p += (size_t)(N + 1) * 4 + 12;
    unsigned* blocksum = (unsigned*)p; p += 512 * 4;
    int2* edata = (int2*)p;            p += (size_t)E * 8;   // packed (src, weight)

    // xb: x converted to bf16 [MPAD][FIN] — reuses the idle m buffer (25.6 MB < 51.2 MB)
    unsigned short* xb = m;

    const int nb = (N + 255) / 256;             // 391
    const int MY = MPAD / 128;                  // 782 row-tiles
    const int ggrid = 16 * ((MY + 7) / 8);      // 1568 (pair-swizzled 1-D grid)

    // ---- Merged prep (conv x, wprep w1, wprep gw, conv w2, zero cnt, foldbias) ----
    prep_k<<<13852, 256, 0, stream>>>(x, xb, w1, w1t, gw, gwt, w2, w2c, b2, foldb, cnt);

    // ---- Fold: fBt[c][k'] = sum_j G0[j][c]*W2[k'][j]  (my=2 -> grid 16, 14 blocks idle)
    gemm_lds_k<HDIM, false, false><<<16, 256, 0, stream>>>(gwt, w2c, nullptr, fBt, 2);

    // ---- CSR build (4 launches) ----
    count_k<<<(E + 255) / 256, 256, 0, stream>>>(dst, cnt, E);
    scan1_k<<<nb, 256, 0, stream>>>(cnt, rs, blocksum, dinv, N);
    scan23_k<<<nb, 256, 0, stream>>>(rs, blocksum, N, E);
    fill_k<<<(E + 255) / 256, 256, 0, stream>>>(src, dst, rs, cnt, dinv, edata, E);

    // ---- Encoder GEMM1: h1 = relu(xb @ W1 + b1) ----
    gemm_lds_k<FIN, true, true><<<ggrid, 256, 0, stream>>>(xb, w1t, b1, h1, MY);

    // ---- Layer 0 (folded): m = h1 @ (W2*G0) + b2*G0  (overwrites xb — already consumed)
    gemm_lds_k<HDIM, true, false><<<ggrid, 256, 0, stream>>>(h1, fBt, foldb, m, MY);
    gather_k<false><<<N / 8, 256, 0, stream>>>(rs, edata, dinv, m, gb, h, N);

    // ---- Layers 1..2 ----
    for (int l = 1; l < NLAYERS; ++l) {
        const unsigned short* wl = gwt + (size_t)l * HDIM * HDIM;
        const float* bl = gb + (size_t)l * HDIM;
        gemm_lds_k<HDIM, false, false><<<ggrid, 256, 0, stream>>>(h, wl, nullptr, m, MY);
        if (l < NLAYERS - 1)
            gather_k<false><<<N / 8, 256, 0, stream>>>(rs, edata, dinv, m, bl, h, N);
        else
            gather_k<true><<<N / 8, 256, 0, stream>>>(rs, edata, dinv, m, bl, d_out, N);
    }
}

// Round 11
// 416.378 us; speedup vs baseline: 1.0637x; 1.0038x over previous
//
#include <hip/hip_runtime.h>
#include <hip/hip_bf16.h>

// Problem constants
#define NNODES 100000
#define NEDGES 300000
#define FIN 128
#define HDIM 256
#define NLAYERS 3
#define MPAD 100096  // 782 * 128 — all GEMMs compute exactly MPAD rows, no predicates

typedef float f32x4 __attribute__((ext_vector_type(4)));
typedef short bf16x8 __attribute__((ext_vector_type(8)));

__device__ inline float bf2f(unsigned short u) {
    union { unsigned int i; float f; } v;
    v.i = ((unsigned int)u) << 16;
    return v.f;
}
__device__ inline unsigned short f2bf(float f) {  // RNE
    union { float f; unsigned int i; } v;
    v.f = f;
    return (unsigned short)((v.i + 0x7fffu + ((v.i >> 16) & 1u)) >> 16);
}

// 16-byte async global->LDS (dest = wave-uniform base + lane*16)
__device__ __forceinline__ void gll16(const unsigned short* g, unsigned short* l) {
    __builtin_amdgcn_global_load_lds(
        (const __attribute__((address_space(1))) unsigned int*)g,
        (__attribute__((address_space(3))) unsigned int*)l, 16, 0, 0);
}

// ---------------------------------------------------------------------------
// Counted-vmcnt pipelined MFMA GEMM (R6/R10 schedule, unchanged) + TAIL-MERGE.
// 128x128 tile, 4 waves, BK=32, TRIPLE-buffered LDS (48 KiB, 3 blocks/CU =
// 768 resident slots).  Per K-step: vmcnt(4) -> s_barrier -> issue stage(t+2)
// -> ds_read buf[t%3] -> 16 MFMA (operand order mfma(a,b) — swapped order
// REGRESSED +20us in R7/R8, do not reintroduce).
// XCD PAIR-SWIZZLE: vb = 16t + 8x + u (u=0..7), ytile = 8t+u; col-pair of a
// row-panel sits 8 apart -> same XCD, co-resident -> A L2-hits (R5, -23us).
// TAIL-MERGE (R11): grid = 1536 = exactly 2 rounds of 768; blocks < nextra
// also process virtual tile vb = bid + gridDim.x (ytile<my guard).  The old
// 1568-grid left a 32-block third round at 4% utilization ≈ +T_b per GEMM.
// __syncthreads() between reps protects LDS re-staging (all waves' rep-0
// ds_reads retired before any rep-1 gll16 lands).
// ---------------------------------------------------------------------------
template <int K, bool BIAS, bool RELU>
__global__ __launch_bounds__(256) void gemm_lds_k(
    const unsigned short* __restrict__ A, const unsigned short* __restrict__ Bt,
    const float* __restrict__ bias, unsigned short* __restrict__ C,
    int my, int nextra) {
    constexpr int BK = 32;        // 64 B per LDS row
    constexpr int NT = K / BK;    // 4 (K=128) or 8 (K=256)
    __shared__ unsigned short sA[3][128 * BK];
    __shared__ unsigned short sB[3][128 * BK];

    const int tid  = threadIdx.x;
    const int lane = tid & 63;
    const int wid  = tid >> 6;
    const int r15  = lane & 15;
    const int kq   = lane >> 4;        // 0..3
    const int wr   = wid >> 1;         // wave row-tile (0/1)
    const int wc   = wid & 1;          // wave col-tile (0/1)

    // Read-side swizzled fragment offsets (tile-independent)
    const int sread = ((kq ^ ((r15 >> 1) & 3)) * 8);
    int aoff[4], boff[4];
#pragma unroll
    for (int i = 0; i < 4; ++i) {
        aoff[i] = (wr * 64 + i * 16 + r15) * BK + sread;
        boff[i] = (wc * 64 + i * 16 + r15) * BK + sread;
    }

    // Staging lane geometry (tile-independent parts): wave w, chunk q covers
    // LDS rows [q*64 + w*16, +16); lane L writes row (L>>2), phys slot (L&3);
    // phys slot p at row r holds logical k-slot p ^ ((r>>1)&3) (involution).
    int rr_[2], slot_[2], ldsbase[2];
#pragma unroll
    for (int q = 0; q < 2; ++q) {
        rr_[q]   = q * 64 + wid * 16 + (lane >> 2);
        slot_[q] = (lane & 3) ^ ((rr_[q] >> 1) & 3);
        ldsbase[q] = (q * 64 + wid * 16) * BK;   // wave-uniform
    }

    const int reps = (blockIdx.x < nextra) ? 2 : 1;
    for (int rep = 0; rep < reps; ++rep) {
        const int vb    = blockIdx.x + rep * gridDim.x;
        const int ytile = (vb >> 4) * 8 + (vb & 7);
        if (ytile < my) {                       // block-uniform guard
            const int xcol  = (vb >> 3) & 1;
            const int rowblk = ytile * 128;
            const int colblk = xcol * 128;

            const unsigned short* gA[2];
            const unsigned short* gB[2];
#pragma unroll
            for (int q = 0; q < 2; ++q) {
                gA[q] = A  + (size_t)(rowblk + rr_[q]) * K + slot_[q] * 8;
                gB[q] = Bt + (size_t)(colblk + rr_[q]) * K + slot_[q] * 8;
            }

            f32x4 acc[4][4] = {};

            // prologue: stage K-tiles 0 and 1 into bufs 0 and 1
#pragma unroll
            for (int q = 0; q < 2; ++q) {
                gll16(gA[q], &sA[0][ldsbase[q]]);
                gll16(gB[q], &sB[0][ldsbase[q]]);
            }
#pragma unroll
            for (int q = 0; q < 2; ++q) {
                gll16(gA[q] + BK, &sA[1][ldsbase[q]]);
                gll16(gB[q] + BK, &sB[1][ldsbase[q]]);
            }

#pragma unroll
            for (int t = 0; t < NT; ++t) {
                // counted drain: stage(t) landed; stage(t+1) stays in flight
                if (t + 1 < NT) {
                    asm volatile("s_waitcnt vmcnt(4)" ::: "memory");
                } else {
                    asm volatile("s_waitcnt vmcnt(0)" ::: "memory");
                }
                __builtin_amdgcn_s_barrier();
                // issue stage(t+2) AFTER the barrier (its buffer's last
                // readers were iter t-1, all retired before this barrier)
                if (t + 2 < NT) {
#pragma unroll
                    for (int q = 0; q < 2; ++q) {
                        gll16(gA[q] + (t + 2) * BK, &sA[(t + 2) % 3][ldsbase[q]]);
                        gll16(gB[q] + (t + 2) * BK, &sB[(t + 2) % 3][ldsbase[q]]);
                    }
                }
                bf16x8 a[4], b[4];
#pragma unroll
                for (int i = 0; i < 4; ++i) a[i] = *(const bf16x8*)&sA[t % 3][aoff[i]];
#pragma unroll
                for (int j = 0; j < 4; ++j) b[j] = *(const bf16x8*)&sB[t % 3][boff[j]];
#pragma unroll
                for (int i = 0; i < 4; ++i)
#pragma unroll
                    for (int j = 0; j < 4; ++j)
                        acc[i][j] = __builtin_amdgcn_mfma_f32_16x16x32_bf16(a[i], b[j], acc[i][j], 0, 0, 0);
            }

            // Epilogue: C/D layout col = lane&15, row = (lane>>4)*4 + reg
#pragma unroll
            for (int i = 0; i < 4; ++i) {
#pragma unroll
                for (int reg = 0; reg < 4; ++reg) {
                    int row = rowblk + wr * 64 + i * 16 + kq * 4 + reg;
#pragma unroll
                    for (int j = 0; j < 4; ++j) {
                        int col = colblk + wc * 64 + j * 16 + r15;
                        float v = acc[i][j][reg];
                        if (BIAS) v += bias[col];
                        if (RELU) v = fmaxf(v, 0.0f);
                        C[(size_t)row * HDIM + col] = f2bf(v);
                    }
                }
            }
        }
        __syncthreads();   // LDS reuse fence between reps (uniform)
    }
}

// ---------------------------------------------------------------------------
// Merged prep kernel, partitioned by blockIdx over 6 independent jobs:
//   [0,12500):      conv x -> xb   (fp32->bf16, x4)   [N*FIN/4 = 3.2M items]
//   [12500,12628):  wprep w1 -> w1t  (transpose+convert, K=FIN)
//   [12628,13396):  wprep gw -> gwt  (3 mats, K=HDIM)
//   [13396,13460):  conv w2 -> w2c
//   [13460,13851):  zero cnt (NNODES)
//   [13851]:        foldbias fb[c] = sum_j b2[j]*G0[j][c]
// ---------------------------------------------------------------------------
__global__ __launch_bounds__(256) void prep_k(
    const float* __restrict__ x, unsigned short* __restrict__ xb,
    const float* __restrict__ w1, unsigned short* __restrict__ w1t,
    const float* __restrict__ gw, unsigned short* __restrict__ gwt,
    const float* __restrict__ w2, unsigned short* __restrict__ w2c,
    const float* __restrict__ b2, float* __restrict__ foldb,
    unsigned* __restrict__ cnt) {
    int b = blockIdx.x;
    int tid = threadIdx.x;
    if (b < 12500) {                     // conv x (x4)
        int i = b * 256 + tid;           // < 3,200,000
        float4 v = ((const float4*)x)[i];
        ushort4 u;
        u.x = f2bf(v.x); u.y = f2bf(v.y); u.z = f2bf(v.z); u.w = f2bf(v.w);
        ((ushort4*)xb)[i] = u;
    } else if (b < 12628) {              // wprep w1: [FIN][256] -> [256][FIN]
        int i = (b - 12500) * 256 + tid; // < 32768
        int k = i >> 8, p = i & 255;
        w1t[(size_t)p * FIN + k] = f2bf(w1[i]);
    } else if (b < 13396) {              // wprep gw: [3][256][256] -> transposed
        int i = (b - 12628) * 256 + tid; // < 196608
        int mat = i >> 16;
        int r = i & 65535;
        int k = r >> 8, p = r & 255;
        gwt[(size_t)mat * 65536 + (size_t)p * HDIM + k] = f2bf(gw[i]);
    } else if (b < 13460) {              // conv w2 (x4): 16384 float4s
        int i = (b - 13396) * 256 + tid;
        float4 v = ((const float4*)w2)[i];
        ushort4 u;
        u.x = f2bf(v.x); u.y = f2bf(v.y); u.z = f2bf(v.z); u.w = f2bf(v.w);
        ((ushort4*)w2c)[i] = u;
    } else if (b < 13851) {              // zero cnt
        int i = (b - 13460) * 256 + tid;
        if (i < NNODES) cnt[i] = 0u;
    } else {                             // foldbias (one block)
        int c = tid;
        float s = 0.0f;
#pragma unroll 8
        for (int j = 0; j < HDIM; ++j) s += b2[j] * gw[(size_t)j * HDIM + c];
        foldb[c] = s;
    }
}

// ---------------------------------------------------------------------------
// CSR build utilities
// ---------------------------------------------------------------------------
__global__ void count_k(const int* __restrict__ dst, unsigned* __restrict__ cnt, int E) {
    int e = blockIdx.x * blockDim.x + threadIdx.x;
    if (e < E) atomicAdd(&cnt[dst[e]], 1u);
}

// scan1 also computes dinv and zeroes cnt (cursor reuse)
__global__ __launch_bounds__(256) void scan1_k(unsigned* __restrict__ cnt,
                                               int* __restrict__ rs,
                                               unsigned* __restrict__ blocksum,
                                               float* __restrict__ dinv, int N) {
    __shared__ unsigned tmp[256];
    int tid = threadIdx.x;
    int gid = blockIdx.x * 256 + tid;
    unsigned v = (gid < N) ? cnt[gid] : 0u;
    if (gid < N) {
        dinv[gid] = 1.0f / sqrtf((float)(v + 1u));  // +1 = self loop
        cnt[gid] = 0u;                               // reset for cursor use
    }
    tmp[tid] = v;
    __syncthreads();
#pragma unroll
    for (int off = 1; off < 256; off <<= 1) {
        unsigned t = (tid >= off) ? tmp[tid - off] : 0u;
        __syncthreads();
        tmp[tid] += t;
        __syncthreads();
    }
    if (gid < N) rs[gid] = (int)(tmp[tid] - v);
    if (tid == 255) blocksum[blockIdx.x] = tmp[tid];
}

// scan23: merged scan2+scan3. Each block b reduces the RAW per-block totals
// blocksum[0..b) itself (<=391 values, strided loads + block reduce), then
// adds that prefix to its rs slice.  Saves one launch.
__global__ __launch_bounds__(256) void scan23_k(int* __restrict__ rs,
                                                const unsigned* __restrict__ blocksum,
                                                int N, int E) {
    const int b = blockIdx.x, tid = threadIdx.x;
    unsigned s = 0;
    for (int i = tid; i < b; i += 256) s += blocksum[i];
    __shared__ unsigned red[4];
#pragma unroll
    for (int off = 32; off > 0; off >>= 1) s += __shfl_down(s, off);
    if ((tid & 63) == 0) red[tid >> 6] = s;
    __syncthreads();
    unsigned pref = red[0] + red[1] + red[2] + red[3];
    int gid = b * 256 + tid;
    if (gid < N) rs[gid] += (int)pref;
    if (gid == N) rs[N] = E;
}

// fill_k packs (src, weight) into one int2 per edge — single 8B load in gather
__global__ void fill_k(const int* __restrict__ src, const int* __restrict__ dst,
                       const int* __restrict__ rs, unsigned* __restrict__ cursor,
                       const float* __restrict__ dinv,
                       int2* __restrict__ edata, int E) {
    int e = blockIdx.x * blockDim.x + threadIdx.x;
    if (e >= E) return;
    int s = src[e], d = dst[e];
    int pos = rs[d] + (int)atomicAdd(&cursor[d], 1u);
    float w = dinv[s] * dinv[d];
    edata[pos] = make_int2(s, __float_as_int(w));
}

// ---------------------------------------------------------------------------
// CSR gather-aggregate (bf16 m), fused self-loop + bias + ReLU.
// TWO nodes per wave (R6 version — best measured): half-wave (32 lanes x
// ushort8 = 512B) per node row.  12500 blocks, 8 nodes/block.
// Cooperative half-wave edge-metadata load + half-wave shuffle broadcast +
// 4-wide unrolled independent row gathers. Masked slots carry (s=0, w=0.0).
// ---------------------------------------------------------------------------
template <bool OUTF32>
__global__ __launch_bounds__(256) void gather_k(const int* __restrict__ rs,
                                                const int2* __restrict__ edata,
                                                const float* __restrict__ dinv,
                                                const unsigned short* __restrict__ m,
                                                const float* __restrict__ bias,
                                                void* __restrict__ out, int N) {
    const int wid  = threadIdx.x >> 6;   // 0..3
    const int lane = threadIdx.x & 63;
    const int half = lane >> 5;          // 0/1: which node of the pair
    const int hl   = lane & 31;          // lane within half
    const int node = blockIdx.x * 8 + wid * 2 + half;

    const int beg = rs[node], end = rs[node + 1];
    const float d = dinv[node];
    const float w0 = d * d;

    // self row: 32 lanes x ushort8 = 512B
    bf16x8 u = ((const bf16x8*)(m + (size_t)node * HDIM))[hl];
    float acc[8];
#pragma unroll
    for (int j = 0; j < 8; ++j) acc[j] = bf2f((unsigned short)u[j]) * w0;

    for (int base = beg; base < end; base += 32) {
        int2 ed = (base + hl < end) ? edata[base + hl] : make_int2(0, 0);
        int take = end - base;
        if (take > 32) take = 32;
        for (int e = 0; e < take; e += 4) {
            // broadcast from this half's metadata lanes
            int s0 = __shfl(ed.x, half * 32 + e + 0);
            int s1 = __shfl(ed.x, half * 32 + e + 1);
            int s2 = __shfl(ed.x, half * 32 + e + 2);
            int s3 = __shfl(ed.x, half * 32 + e + 3);
            float wq0 = __int_as_float(__shfl(ed.y, half * 32 + e + 0));
            float wq1 = __int_as_float(__shfl(ed.y, half * 32 + e + 1));
            float wq2 = __int_as_float(__shfl(ed.y, half * 32 + e + 2));
            float wq3 = __int_as_float(__shfl(ed.y, half * 32 + e + 3));
            bf16x8 v0 = ((const bf16x8*)(m + (size_t)s0 * HDIM))[hl];
            bf16x8 v1 = ((const bf16x8*)(m + (size_t)s1 * HDIM))[hl];
            bf16x8 v2 = ((const bf16x8*)(m + (size_t)s2 * HDIM))[hl];
            bf16x8 v3 = ((const bf16x8*)(m + (size_t)s3 * HDIM))[hl];
#pragma unroll
            for (int j = 0; j < 8; ++j) {
                acc[j] += bf2f((unsigned short)v0[j]) * wq0;
                acc[j] += bf2f((unsigned short)v1[j]) * wq1;
                acc[j] += bf2f((unsigned short)v2[j]) * wq2;
                acc[j] += bf2f((unsigned short)v3[j]) * wq3;
            }
        }
    }

    // bias + ReLU on 8 cols (hl*8 .. hl*8+7)
    float4 b0 = ((const float4*)bias)[hl * 2];
    float4 b1 = ((const float4*)bias)[hl * 2 + 1];
    acc[0] = fmaxf(acc[0] + b0.x, 0.0f); acc[1] = fmaxf(acc[1] + b0.y, 0.0f);
    acc[2] = fmaxf(acc[2] + b0.z, 0.0f); acc[3] = fmaxf(acc[3] + b0.w, 0.0f);
    acc[4] = fmaxf(acc[4] + b1.x, 0.0f); acc[5] = fmaxf(acc[5] + b1.y, 0.0f);
    acc[6] = fmaxf(acc[6] + b1.z, 0.0f); acc[7] = fmaxf(acc[7] + b1.w, 0.0f);

    if (OUTF32) {
        float4 o0 = {acc[0], acc[1], acc[2], acc[3]};
        float4 o1 = {acc[4], acc[5], acc[6], acc[7]};
        ((float4*)out)[(size_t)node * 64 + hl * 2] = o0;
        ((float4*)out)[(size_t)node * 64 + hl * 2 + 1] = o1;
    } else {
        bf16x8 o;
#pragma unroll
        for (int j = 0; j < 8; ++j) o[j] = (short)f2bf(acc[j]);
        ((bf16x8*)out)[(size_t)node * 32 + hl] = o;
    }
}

extern "C" void kernel_launch(void* const* d_in, const int* in_sizes, int n_in,
                              void* d_out, int out_size, void* d_ws, size_t ws_size,
                              hipStream_t stream) {
    const float* x  = (const float*)d_in[0];
    const int* ei   = (const int*)d_in[1];
    const float* w1 = (const float*)d_in[2];
    const float* b1 = (const float*)d_in[3];
    const float* w2 = (const float*)d_in[4];
    const float* b2 = (const float*)d_in[5];
    const float* gw = (const float*)d_in[6];
    const float* gb = (const float*)d_in[7];

    const int N = NNODES, E = NEDGES;
    const int* src = ei;
    const int* dst = ei + E;

    // Workspace layout (~158 MB)
    char* p = (char*)d_ws;
    unsigned short* h1   = (unsigned short*)p; p += (size_t)MPAD * HDIM * 2;  // 51.2 MB
    unsigned short* h    = (unsigned short*)p; p += (size_t)MPAD * HDIM * 2;
    unsigned short* m    = (unsigned short*)p; p += (size_t)MPAD * HDIM * 2;
    unsigned short* w1t  = (unsigned short*)p; p += (size_t)FIN * HDIM * 2;
    unsigned short* gwt  = (unsigned short*)p; p += (size_t)NLAYERS * HDIM * HDIM * 2;
    unsigned short* w2c  = (unsigned short*)p; p += (size_t)HDIM * HDIM * 2;   // w2 bf16 row-major
    unsigned short* fBt  = (unsigned short*)p; p += (size_t)HDIM * HDIM * 2;   // folded W2*G0, Bt layout
    float* foldb = (float*)p;          p += (size_t)HDIM * 4;                  // folded bias b2*G0
    unsigned* cnt = (unsigned*)p;      p += (size_t)N * 4;
    float* dinv = (float*)p;           p += (size_t)N * 4;
    int* rs = (int*)p;                 p += (size_t)(N + 1) * 4 + 12;
    unsigned* blocksum = (unsigned*)p; p += 512 * 4;
    int2* edata = (int2*)p;            p += (size_t)E * 8;   // packed (src, weight)

    // xb: x converted to bf16 [MPAD][FIN] — reuses the idle m buffer (25.6 MB < 51.2 MB)
    unsigned short* xb = m;

    const int nb = (N + 255) / 256;             // 391
    const int MY = MPAD / 128;                  // 782 row-tiles (1564 tiles)
    const int ggrid = 1536;                     // exactly 2 x 768 resident slots
    const int nextra = 32;                      // blocks 0..31 take vb=bid+1536 (4 guarded off)

    // ---- Merged prep (conv x, wprep w1, wprep gw, conv w2, zero cnt, foldbias) ----
    prep_k<<<13852, 256, 0, stream>>>(x, xb, w1, w1t, gw, gwt, w2, w2c, b2, foldb, cnt);

    // ---- Fold: fBt[c][k'] = sum_j G0[j][c]*W2[k'][j]  (my=2 -> 4 active blocks)
    gemm_lds_k<HDIM, false, false><<<16, 256, 0, stream>>>(gwt, w2c, nullptr, fBt, 2, 0);

    // ---- CSR build (4 launches) ----
    count_k<<<(E + 255) / 256, 256, 0, stream>>>(dst, cnt, E);
    scan1_k<<<nb, 256, 0, stream>>>(cnt, rs, blocksum, dinv, N);
    scan23_k<<<nb, 256, 0, stream>>>(rs, blocksum, N, E);
    fill_k<<<(E + 255) / 256, 256, 0, stream>>>(src, dst, rs, cnt, dinv, edata, E);

    // ---- Encoder GEMM1: h1 = relu(xb @ W1 + b1) ----
    gemm_lds_k<FIN, true, true><<<ggrid, 256, 0, stream>>>(xb, w1t, b1, h1, MY, nextra);

    // ---- Layer 0 (folded): m = h1 @ (W2*G0) + b2*G0  (overwrites xb — already consumed)
    gemm_lds_k<HDIM, true, false><<<ggrid, 256, 0, stream>>>(h1, fBt, foldb, m, MY, nextra);
    gather_k<false><<<N / 8, 256, 0, stream>>>(rs, edata, dinv, m, gb, h, N);

    // ---- Layers 1..2 ----
    for (int l = 1; l < NLAYERS; ++l) {
        const unsigned short* wl = gwt + (size_t)l * HDIM * HDIM;
        const float* bl = gb + (size_t)l * HDIM;
        gemm_lds_k<HDIM, false, false><<<ggrid, 256, 0, stream>>>(h, wl, nullptr, m, MY, nextra);
        if (l < NLAYERS - 1)
            gather_k<false><<<N / 8, 256, 0, stream>>>(rs, edata, dinv, m, bl, h, N);
        else
            gather_k<true><<<N / 8, 256, 0, stream>>>(rs, edata, dinv, m, bl, d_out, N);
    }
}